// Round 10
// baseline (294.821 us; speedup 1.0000x reference)
//
#include <hip/hip_runtime.h>

// IntrospectiveAttention on MI355X (gfx950).
// The growing KV cache is dead code (mask = -inf past L); each layer is plain
// causal attention over its own fresh q/k/v. Pipeline:
//   0) cvt_k:     fp32 -> bf16 pre-convert of x/Wq/Wk/Wv/Wo
//   1) gemm_k<0>: QKV projections, global_load_lds staging with XOR-swizzled
//                 LDS (r9: conflicts 1.4e7 -> 1.5e5), q: rope*(SCALE*log2e);
//                 k: rope; v: two-pass LDS transpose -> VT
//   2) attn_k:    BARRIER-FREE flash attention: K/V MFMA B-fragments stream
//                 directly global->VGPR (each wave consumes whole KV tiles;
//                 8 blocks share each tile via L2 -> no LDS staging value).
//                 Zero __syncthreads; only wave-private Ps round-trip in LDS.
//                 No-max exp2 softmax, row sums via ones-MFMA, qt pairing.
//   3) combine_k: rmsnorm*lw sum + alpha*x + final rmsnorm -> bf16 xn
//   4) gemm_k<1>: xn @ Wo^T -> fp32 d_out

#define B_  2
#define L_  1024
#define E_  1024
#define H_  16
#define NL_ 3
#define D_  64

typedef __bf16 bf16_t;
typedef __bf16 bf16x8 __attribute__((ext_vector_type(8)));
typedef __bf16 bf16x4 __attribute__((ext_vector_type(4)));
typedef float  f32x4  __attribute__((ext_vector_type(4)));

#define NEG_INF (-__builtin_inff())

typedef const __attribute__((address_space(1))) void* gas_ptr;
typedef __attribute__((address_space(3))) void* las_ptr;

// async global->LDS, 16B per lane; HW dest = wave-uniform base + lane*16
#define GLD_LDS16(gp, lp) \
  __builtin_amdgcn_global_load_lds((gas_ptr)(gp), (las_ptr)(lp), 16, 0, 0)

// ---------------------------------------------------------------------------
// fp32 -> bf16 convert: segs = Wq/Wk/Wv (3,145,728 ea), Wo (1,048,576),
// x (2,097,152). grid (3072, 5) x 256, 4 elems/thread.
// ---------------------------------------------------------------------------
__global__ __launch_bounds__(256) void cvt_k(
    const float* __restrict__ s0, const float* __restrict__ s1,
    const float* __restrict__ s2, const float* __restrict__ s3,
    const float* __restrict__ s4, bf16_t* __restrict__ d0,
    bf16_t* __restrict__ d1, bf16_t* __restrict__ d2, bf16_t* __restrict__ d3,
    bf16_t* __restrict__ d4)
{
  const int seg = blockIdx.y;
  const float* s;
  bf16_t* d;
  int n;
  if (seg == 0)      { s = s0; d = d0; n = 3145728; }
  else if (seg == 1) { s = s1; d = d1; n = 3145728; }
  else if (seg == 2) { s = s2; d = d2; n = 3145728; }
  else if (seg == 3) { s = s3; d = d3; n = 1048576; }
  else               { s = s4; d = d4; n = 2097152; }
  const int i = (blockIdx.x * 256 + threadIdx.x) * 4;
  if (i < n) {
    const float4 v = *(const float4*)(s + i);
    bf16x4 o;
    o[0] = (bf16_t)v.x; o[1] = (bf16_t)v.y; o[2] = (bf16_t)v.z; o[3] = (bf16_t)v.w;
    *(bf16x4*)(d + i) = o;
  }
}

// ---------------------------------------------------------------------------
// GEMM: C = X (M x K) * W^T, X/W bf16 row-major (W is N x K). 128x128 tile,
// BK=64, global_load_lds width-16 staging with XOR swizzle:
//   LDS[row][g] = Global[row][g ^ (row&7)]  (8-elem col groups)
// EPI==0: 9 QKV mats. t==0 (q): rope * SCALE*log2e; t==1 (k): rope;
//         t==2 (v): two-pass transpose -> VT[il][b][h][d][l].
// EPI==1: fp32 accumulator store to outf (Wo projection -> d_out).
// ---------------------------------------------------------------------------
template <int EPI>
__global__ __launch_bounds__(256) void gemm_k(
    const bf16_t* __restrict__ X, const bf16_t* __restrict__ W0,
    const bf16_t* __restrict__ W1, const bf16_t* __restrict__ W2,
    const float* __restrict__ cosb, const float* __restrict__ sinb,
    bf16_t* __restrict__ qk, bf16_t* __restrict__ vt, float* __restrict__ outf)
{
  // staging: Xs = smem[0..8191], Ws = smem[8192..16383]  (32 KB total)
  // V-transpose view: S[128][72] (18.4 KB), reused after K-loop
  __shared__ bf16_t smem[128 * 128];
  bf16_t* Xs = smem;
  bf16_t* Ws = smem + 8192;
  const int tid = threadIdx.x;
  const int lane = tid & 63;
  const int w = tid >> 6;
  const int q4 = lane >> 4, l15 = lane & 15;
  const int l7 = l15 & 7;
  const int row0 = blockIdx.x * 128;

  int g, tileN;
  const bf16_t* Wb;
  if (EPI == 0) {
    g = blockIdx.y >> 3;
    tileN = blockIdx.y & 7;
    const int t = g % 3, il = g / 3;
    Wb = (t == 0 ? W0 : (t == 1 ? W1 : W2)) + (size_t)il * E_ * E_;
  } else {
    g = 0;
    tileN = blockIdx.y;
    Wb = W0;
  }
  const int col0 = tileN * 128;
  const int rA = (w & 1) * 64;   // wave's row sub-tile
  const int cB = (w >> 1) * 64;  // wave's col sub-tile

  // staging geometry (swizzled global column group)
  const int srow = tid >> 3;                      // row within 32-row slab
  const int scol = (((tid & 7) ^ (srow & 7)) << 3);  // global col for LDS slot

  f32x4 acc[4][4] = {};

  for (int k0 = 0; k0 < E_; k0 += 64) {
    __syncthreads();  // previous iteration's LDS reads done
#pragma unroll
    for (int it = 0; it < 4; ++it) {
      const int flat = it * 2048 + tid * 8;
      const int r = it * 32 + srow;
      GLD_LDS16(X + (size_t)(row0 + r) * E_ + k0 + scol, &Xs[flat]);
      GLD_LDS16(Wb + (size_t)(col0 + r) * E_ + k0 + scol, &Ws[flat]);
    }
    __syncthreads();  // staging complete
#pragma unroll
    for (int kk = 0; kk < 2; ++kk) {
      bf16x8 a[4], b[4];
      const int cg = ((kk * 4 + q4) ^ l7) << 3;  // swizzled col offset
#pragma unroll
      for (int mi = 0; mi < 4; ++mi)
        a[mi] = *(const bf16x8*)&Xs[(rA + mi * 16 + l15) * 64 + cg];
#pragma unroll
      for (int ni = 0; ni < 4; ++ni)
        b[ni] = *(const bf16x8*)&Ws[(cB + ni * 16 + l15) * 64 + cg];
#pragma unroll
      for (int mi = 0; mi < 4; ++mi)
#pragma unroll
        for (int ni = 0; ni < 4; ++ni)
          acc[mi][ni] =
              __builtin_amdgcn_mfma_f32_16x16x32_bf16(a[mi], b[ni], acc[mi][ni], 0, 0, 0);
    }
  }

  if (EPI == 0) {
    const int t = g % 3, il = g / 3;
    if (t < 2) {  // q,k: rope epilogue, [slot][b][h][l][d]
      const int slot = il * 2 + t;
      const int h = tileN * 2 + (w >> 1);  // head constant per wave
      // q: SCALE (0.125) * log2(e) folded in (attn softmax runs in exp2 domain)
      const float post = (t == 0) ? 0.18033688011112042f : 1.0f;
#pragma unroll
      for (int mi = 0; mi < 4; ++mi) {
#pragma unroll
        for (int reg = 0; reg < 4; ++reg) {
          const int m = row0 + rA + mi * 16 + q4 * 4 + reg;
          const int b = m >> 10, l = m & (L_ - 1);
#pragma unroll
          for (int ni = 0; ni < 4; ++ni) {
            const int d = ni * 16 + l15;
            const float v0 = acc[mi][ni][reg];
            const float part = acc[mi][ni ^ 2][reg];  // value at d^32, same lane
            const float rot = (d < 32) ? -part : part;
            const float v = (v0 * cosb[l * D_ + d] + rot * sinb[l * D_ + d]) * post;
            qk[(((size_t)slot * B_ + b) * H_ + h) * ((size_t)L_ * D_) +
               (size_t)l * D_ + d] = (bf16_t)v;
          }
        }
      }
    } else {  // v: two-pass transpose via S[128][72] -> VT[il][b][h][d][l]
      const int n_l = tid >> 1, lh = tid & 1;
      const int h = tileN * 2 + (n_l >> 6), d = n_l & 63;
      const int bb = row0 >> 10;
      __syncthreads();  // all waves done reading Xs/Ws
#pragma unroll
      for (int p = 0; p < 2; ++p) {
        if ((w & 1) == p) {  // waves whose rA == p*64 own this m-half
#pragma unroll
          for (int mi = 0; mi < 4; ++mi)
#pragma unroll
            for (int reg = 0; reg < 4; ++reg)
#pragma unroll
              for (int ni = 0; ni < 4; ++ni)
                smem[(cB + ni * 16 + l15) * 72 + mi * 16 + q4 * 4 + reg] =
                    (bf16_t)acc[mi][ni][reg];
        }
        __syncthreads();
        // read-out: thread -> row n = tid>>1 (h,d), half lh = tid&1 (32 l)
        const int l0 = (row0 & (L_ - 1)) + p * 64 + lh * 32;
        bf16_t* gp = vt + (((size_t)il * B_ + bb) * H_ + h) * ((size_t)D_ * L_) +
                     (size_t)d * L_ + l0;
        const bf16_t* sp = &smem[n_l * 72 + lh * 32];
#pragma unroll
        for (int c = 0; c < 4; ++c)
          *(bf16x8*)(gp + c * 8) = *(const bf16x8*)(sp + c * 8);
        if (p == 0) __syncthreads();  // before overwriting S with half 1
      }
    }
  } else {
#pragma unroll
    for (int mi = 0; mi < 4; ++mi) {
#pragma unroll
      for (int reg = 0; reg < 4; ++reg) {
        const int m = row0 + rA + mi * 16 + q4 * 4 + reg;
#pragma unroll
        for (int ni = 0; ni < 4; ++ni) {
          const int n = col0 + cB + ni * 16 + l15;
          outf[(size_t)m * E_ + n] = acc[mi][ni][reg];  // fp32 output
        }
      }
    }
  }
}

// ---------------------------------------------------------------------------
// Flash attention, BARRIER-FREE. BQ=64 / BK=64, complementary-qt pairing
// (block x: q-tile 15-x then x -> uniform 17 tiles). Each wave owns 16 q rows.
// K/V MFMA B-fragments load DIRECTLY global->VGPR: per-lane 16 B from row
// (ni*16+l15), cols (kk*32+q4*8) -> 16 fully-used 128 B segments per wave.
// Each KV tile is shared by 8 blocks -> L2-resident; no LDS staging, hence no
// __syncthreads anywhere: waves run free, TLP hides L2 latency. Only the
// wave-private Ps round-trip (P C-layout -> A-layout) uses LDS (lgkmcnt wait).
// No-max exp2 softmax (q pre-scaled by SCALE*log2e; scores bounded), row sums
// via MFMA against all-ones fragment.
// ---------------------------------------------------------------------------
__global__ __launch_bounds__(256) void attn_k(const bf16_t* __restrict__ qk,
                                              const bf16_t* __restrict__ vt,
                                              bf16_t* __restrict__ attn)
{
  __shared__ bf16_t Ps[4][16 * 72];  // per-wave 16x64 P tile, padded rows

  const int tid = threadIdx.x, lane = tid & 63, w = tid >> 6;
  const int q4 = lane >> 4, l15 = lane & 15;
  const int x = blockIdx.x;  // 0..7
  const int by = blockIdx.y;
  const int h = by & 15, b = (by >> 4) & 1, i = by >> 5;
  const size_t HD = (size_t)L_ * D_;
  const bf16_t* Qp = qk + (((size_t)(i * 2 + 0) * B_ + b) * H_ + h) * HD;
  const bf16_t* Kp = qk + (((size_t)(i * 2 + 1) * B_ + b) * H_ + h) * HD;
  const bf16_t* Vp = vt + (((size_t)i * B_ + b) * H_ + h) * HD;  // [d][l]

  // fragment offsets (per lane)
  const int kfrag = (l15 * 64) + q4 * 8;            // K row l15, col q4*8
  const size_t vfrag = (size_t)l15 * L_ + q4 * 8;   // VT row (d) l15, col q4*8

  // all-ones B fragment for row sums
  bf16x8 ones;
#pragma unroll
  for (int jj = 0; jj < 8; ++jj) ones[jj] = (bf16_t)1.0f;

#pragma unroll 1
  for (int ph = 0; ph < 2; ++ph) {
    const int qt = ph == 0 ? (15 - x) : x;  // paired: 17 tiles total

    // Q fragments in registers (A-layout: row = l15, k = q4*8 within kk-half)
    bf16x8 aq[2];
#pragma unroll
    for (int kk = 0; kk < 2; ++kk)
      aq[kk] = *(const bf16x8*)(Qp + (size_t)(qt * 64 + w * 16 + l15) * 64 +
                                kk * 32 + q4 * 8);

    f32x4 o[4] = {};
    f32x4 lacc = {};

#pragma unroll 1
    for (int j = 0; j <= qt; ++j) {
      const bf16_t* kbase = Kp + j * 4096 + kfrag;
      const bf16_t* vbase = Vp + j * 64 + vfrag;

      // K fragments for this tile (global -> VGPR; L2-hot, 8-block reuse)
      bf16x8 bk[2][4];
#pragma unroll
      for (int kk = 0; kk < 2; ++kk)
#pragma unroll
        for (int ni = 0; ni < 4; ++ni)
          bk[kk][ni] = *(const bf16x8*)(kbase + ni * 1024 + kk * 32);

      // S = Q K^T
      f32x4 s[4] = {};
#pragma unroll
      for (int kk = 0; kk < 2; ++kk)
#pragma unroll
        for (int ni = 0; ni < 4; ++ni)
          s[ni] = __builtin_amdgcn_mfma_f32_16x16x32_bf16(aq[kk], bk[kk][ni],
                                                          s[ni], 0, 0, 0);

      // V^T fragments (issued early; consumed after softmax -> latency hidden)
      bf16x8 bv[2][4];
#pragma unroll
      for (int kk = 0; kk < 2; ++kk)
#pragma unroll
        for (int di = 0; di < 4; ++di)
          bv[kk][di] = *(const bf16x8*)(vbase + (size_t)di * 16384 + kk * 32);

      if (j == qt) {  // diagonal tile: mask cols > row within tile
#pragma unroll
        for (int reg = 0; reg < 4; ++reg)
#pragma unroll
          for (int ni = 0; ni < 4; ++ni)
            if (ni * 16 + l15 > w * 16 + q4 * 4 + reg) s[ni][reg] = NEG_INF;
      }

      // P = exp2(s) (no max subtraction; bounded scores), store to Ps
#pragma unroll
      for (int reg = 0; reg < 4; ++reg)
#pragma unroll
        for (int ni = 0; ni < 4; ++ni)
          Ps[w][(q4 * 4 + reg) * 72 + ni * 16 + l15] = (bf16_t)exp2f(s[ni][reg]);
      // Ps is wave-private: LDS write->read completion only
      asm volatile("s_waitcnt lgkmcnt(0)" ::: "memory");

      // O += P V ; l += P . 1
#pragma unroll
      for (int kk = 0; kk < 2; ++kk) {
        const bf16x8 ap = *(const bf16x8*)&Ps[w][l15 * 72 + kk * 32 + q4 * 8];
        lacc = __builtin_amdgcn_mfma_f32_16x16x32_bf16(ap, ones, lacc, 0, 0, 0);
#pragma unroll
        for (int di = 0; di < 4; ++di)
          o[di] = __builtin_amdgcn_mfma_f32_16x16x32_bf16(ap, bv[kk][di],
                                                          o[di], 0, 0, 0);
      }
    }

    const int row_base = (i * B_ + b) * L_ + qt * 64 + w * 16 + q4 * 4;
#pragma unroll
    for (int reg = 0; reg < 4; ++reg) {
      const float inv = 1.f / lacc[reg];
      const int r = row_base + reg;
#pragma unroll
      for (int di = 0; di < 4; ++di)
        attn[(size_t)r * E_ + h * 64 + di * 16 + l15] = (bf16_t)(o[di][reg] * inv);
    }
  }
}

// ---------------------------------------------------------------------------
// Combine: per (b,l) row: sum_i rmsnorm(a_i)*g_ln[i]*lw[i] + alpha*x, then
// final rmsnorm with g_final -> bf16 row (input to Wo GEMM).
// ---------------------------------------------------------------------------
__device__ __forceinline__ float block_sum(float v, float* sm)
{
#pragma unroll
  for (int off = 32; off > 0; off >>= 1) v += __shfl_xor(v, off);
  const int w = threadIdx.x >> 6;
  __syncthreads();
  if ((threadIdx.x & 63) == 0) sm[w] = v;
  __syncthreads();
  return sm[0] + sm[1] + sm[2] + sm[3];
}

__global__ __launch_bounds__(256) void combine_k(
    const bf16_t* __restrict__ attn, const float* __restrict__ x,
    const float* __restrict__ g_ln, const float* __restrict__ lambdas,
    const float* __restrict__ g_final, const float* __restrict__ alphap,
    bf16_t* __restrict__ xn)
{
  __shared__ float sm[4];
  const int row = blockIdx.x;
  const int tid = threadIdx.x;

  // lambda weights: sigmoid -> non-affine LayerNorm over NL=3
  float sg[3], lw[3];
#pragma unroll
  for (int i = 0; i < 3; ++i) sg[i] = 1.f / (1.f + expf(-lambdas[i]));
  const float mean = (sg[0] + sg[1] + sg[2]) * (1.f / 3.f);
  const float var = ((sg[0] - mean) * (sg[0] - mean) + (sg[1] - mean) * (sg[1] - mean) +
                     (sg[2] - mean) * (sg[2] - mean)) * (1.f / 3.f);
  const float rv = rsqrtf(var + 1e-5f);
#pragma unroll
  for (int i = 0; i < 3; ++i) lw[i] = (sg[i] - mean) * rv;

  const float av = alphap[0];
  float c[4];
#pragma unroll
  for (int k = 0; k < 4; ++k) {
    const int e = tid + k * 256;
    c[k] = av * x[(size_t)row * E_ + e];
  }

  for (int i = 0; i < 3; ++i) {
    float a[4];
    float ss = 0.f;
#pragma unroll
    for (int k = 0; k < 4; ++k) {
      const int e = tid + k * 256;
      a[k] = (float)attn[((size_t)i * (B_ * L_) + row) * E_ + e];
      ss += a[k] * a[k];
    }
    ss = block_sum(ss, sm);
    const float rinv = rsqrtf(ss * (1.f / (float)E_) + 1e-5f);
#pragma unroll
    for (int k = 0; k < 4; ++k) {
      const int e = tid + k * 256;
      c[k] += a[k] * rinv * g_ln[i * E_ + e] * lw[i];
    }
  }

  float ss = 0.f;
#pragma unroll
  for (int k = 0; k < 4; ++k) ss += c[k] * c[k];
  ss = block_sum(ss, sm);
  const float rinv = rsqrtf(ss * (1.f / (float)E_) + 1e-5f);
#pragma unroll
  for (int k = 0; k < 4; ++k) {
    const int e = tid + k * 256;
    xn[(size_t)row * E_ + e] = (bf16_t)(c[k] * rinv * g_final[e]);
  }
}

// ---------------------------------------------------------------------------
extern "C" void kernel_launch(void* const* d_in, const int* in_sizes, int n_in,
                              void* d_out, int out_size, void* d_ws, size_t ws_size,
                              hipStream_t stream)
{
  const float* x       = (const float*)d_in[0];
  const float* cosb    = (const float*)d_in[1];
  const float* sinb    = (const float*)d_in[2];
  // d_in[3] attn_mask: unused (causal mask applied analytically)
  const float* Wq      = (const float*)d_in[4];
  const float* Wk      = (const float*)d_in[5];
  const float* Wv      = (const float*)d_in[6];
  const float* g_ln    = (const float*)d_in[7];
  const float* lambdas = (const float*)d_in[8];
  const float* Wo      = (const float*)d_in[9];
  const float* g_final = (const float*)d_in[10];
  const float* alphap  = (const float*)d_in[11];

  // ws layout (bytes) — 75,497,472 total:
  //   qk    bf16 [6][B][H][L][D]  @ 0           25,165,824
  //   VT    bf16 [3][B][H][D][L]  @ 25,165,824  12,582,912
  //   attnb bf16 [3][B*L][E]      @ 37,748,736  12,582,912
  //   Wqkvb bf16 [3][NL][E][E]    @ 50,331,648  18,874,368
  //   Wob   bf16 [E][E]           @ 69,206,016   2,097,152
  //   xb    bf16 [B*L][E]         @ 71,303,168   4,194,304
  //   xnb   bf16 [B*L][E]         @ 0 (aliases dead qk)
  bf16_t* qk    = (bf16_t*)d_ws;
  bf16_t* VT    = (bf16_t*)((char*)d_ws + 25165824);
  bf16_t* attnb = (bf16_t*)((char*)d_ws + 37748736);
  bf16_t* Wqb   = (bf16_t*)((char*)d_ws + 50331648);
  bf16_t* Wkb   = Wqb + 3145728;
  bf16_t* Wvb   = Wkb + 3145728;
  bf16_t* Wob   = (bf16_t*)((char*)d_ws + 69206016);
  bf16_t* xb    = (bf16_t*)((char*)d_ws + 71303168);
  bf16_t* xnb   = (bf16_t*)d_ws;  // alias: qk dead after attn_k
  float*  out   = (float*)d_out;   // reference output dtype is float32

  // 0) fp32 -> bf16 conversion of weights + x
  cvt_k<<<dim3(3072, 5), 256, 0, stream>>>(Wq, Wk, Wv, Wo, x, Wqb, Wkb, Wvb, Wob, xb);
  // 1) QKV projections + rope / V-transpose: grid (16, 9 mats * 8 col-tiles)
  gemm_k<0><<<dim3(16, 72), 256, 0, stream>>>(xb, Wqb, Wkb, Wvb, cosb, sinb,
                                              qk, VT, nullptr);
  // 2) flash attention: grid (8 paired q-tiles, NL*B*H = 96)
  attn_k<<<dim3(8, 96), 256, 0, stream>>>(qk, VT, attnb);
  // 3) combine + final rmsnorm: one block per (b,l) row
  combine_k<<<dim3(B_ * L_), 256, 0, stream>>>(attnb, x, g_ln, lambdas, g_final,
                                               alphap, xnb);
  // 4) output projection @ Wo^T -> fp32 d_out
  gemm_k<1><<<dim3(16, 8), 256, 0, stream>>>(xnb, Wob, Wob, Wob, cosb, sinb,
                                             nullptr, nullptr, out);
}